// Round 1
// baseline (2997.191 us; speedup 1.0000x reference)
//
#include <hip/hip_runtime.h>
#include <math.h>

// GCN 2-layer: N=100000 nodes, E=3200000 edges, F_IN=256, HID=32, F_OUT=64
// inputs: x[N,256] f32, edge_index[2,E] i32, W1[256,32], b1[32], W2[32,64], b2[64]
// output: [N,64] f32

__global__ void k_deg_init(float* deg, int n) {
    int i = blockIdx.x * blockDim.x + threadIdx.x;
    if (i < n) deg[i] = 1.0f;   // self-loop contributes 1 to every node's degree
}

__global__ void k_deg_count(const int* __restrict__ col, float* deg, int e) {
    int i = blockIdx.x * blockDim.x + threadIdx.x;
    if (i < e) atomicAdd(&deg[col[i]], 1.0f);
}

__global__ void k_dinv(float* deg, int n) {
    int i = blockIdx.x * blockDim.x + threadIdx.x;
    if (i < n) deg[i] = 1.0f / sqrtf(deg[i]);   // deg >= 1 always (self-loop)
}

// xw[node,k] = dot(x[node,:], W1[:,k]);  one thread per output element
__global__ void k_xw(const float* __restrict__ x, const float* __restrict__ W1,
                     float* __restrict__ xw, int n) {
    int idx = blockIdx.x * blockDim.x + threadIdx.x;
    int node = idx >> 5, k = idx & 31;
    if (node >= n) return;
    const float* xr = x + (size_t)node * 256;
    float s = 0.f;
#pragma unroll 8
    for (int i = 0; i < 256; ++i) s += xr[i] * W1[i * 32 + k];
    xw[(size_t)idx] = s;
}

// dst[i,:] = dinv[i]^2 * src[i,:]   (self-loop term, also initializes dst)
__global__ void k_selfinit(const float* __restrict__ src, const float* __restrict__ dinv,
                           float* __restrict__ dst, int n) {
    int idx = blockIdx.x * blockDim.x + threadIdx.x;
    if (idx >= n * 32) return;
    int node = idx >> 5;
    float d = dinv[node];
    dst[idx] = d * d * src[idx];
}

// per (edge, float4-chunk): dst[col,:] += dinv[row]*dinv[col]*src[row,:]
__global__ void k_scatter(const int* __restrict__ rows, const int* __restrict__ cols,
                          const float* __restrict__ dinv, const float* __restrict__ src,
                          float* dst, int e) {
    int idx = blockIdx.x * blockDim.x + threadIdx.x;
    int eidx = idx >> 3, c = idx & 7;
    if (eidx >= e) return;
    int r = rows[eidx], cl = cols[eidx];
    float nrm = dinv[r] * dinv[cl];
    float4 v = ((const float4*)src)[(size_t)r * 8 + c];
    float* dp = dst + (size_t)cl * 32 + c * 4;
    atomicAdd(dp + 0, nrm * v.x);
    atomicAdd(dp + 1, nrm * v.y);
    atomicAdd(dp + 2, nrm * v.z);
    atomicAdd(dp + 3, nrm * v.w);
}

__global__ void k_bias_relu(float* h, const float* __restrict__ b1, int n) {
    int idx = blockIdx.x * blockDim.x + threadIdx.x;
    if (idx >= n * 32) return;
    float v = h[idx] + b1[idx & 31];
    h[idx] = v > 0.f ? v : 0.f;
}

// out[node,j] = dot(fr[node,:32], W2[:,j]) + b2[j]
__global__ void k_out(const float* __restrict__ fr, const float* __restrict__ W2,
                      const float* __restrict__ b2, float* __restrict__ out, int n) {
    int idx = blockIdx.x * blockDim.x + threadIdx.x;
    int node = idx >> 6, j = idx & 63;
    if (node >= n) return;
    const float* f = fr + (size_t)node * 32;
    float s = b2[j];
#pragma unroll
    for (int i = 0; i < 32; ++i) s += f[i] * W2[i * 64 + j];
    out[idx] = s;
}

extern "C" void kernel_launch(void* const* d_in, const int* in_sizes, int n_in,
                              void* d_out, int out_size, void* d_ws, size_t ws_size,
                              hipStream_t stream) {
    const float* x  = (const float*)d_in[0];
    const int*   ei = (const int*)d_in[1];
    const float* W1 = (const float*)d_in[2];
    const float* b1 = (const float*)d_in[3];
    const float* W2 = (const float*)d_in[4];
    const float* b2 = (const float*)d_in[5];
    float* out = (float*)d_out;

    const int N = in_sizes[0] / 256;
    const int E = in_sizes[1] / 2;
    const int* rows = ei;          // edge_index[0]
    const int* cols = ei + E;      // edge_index[1]

    // workspace layout (floats): dinv[N] | xw[N*32] | bufA[N*32] | bufB[N*32]
    float* dinv = (float*)d_ws;
    float* xw   = dinv + N;
    float* bufA = xw + (size_t)N * 32;   // agg1 -> h (in place)
    float* bufB = bufA + (size_t)N * 32; // agg2 (fr)

    const int B = 256;
    // 1. degrees -> dinv
    k_deg_init<<<(N + B - 1) / B, B, 0, stream>>>(dinv, N);
    k_deg_count<<<(E + B - 1) / B, B, 0, stream>>>(cols, dinv, E);
    k_dinv<<<(N + B - 1) / B, B, 0, stream>>>(dinv, N);
    // 2. xw = x @ W1
    k_xw<<<((size_t)N * 32 + B - 1) / B, B, 0, stream>>>(x, W1, xw, N);
    // 3. aggregate 1: bufA = selfloop + scatter
    k_selfinit<<<((size_t)N * 32 + B - 1) / B, B, 0, stream>>>(xw, dinv, bufA, N);
    k_scatter<<<((size_t)E * 8 + B - 1) / B, B, 0, stream>>>(rows, cols, dinv, xw, bufA, E);
    // 4. bias + relu in place -> h
    k_bias_relu<<<((size_t)N * 32 + B - 1) / B, B, 0, stream>>>(bufA, b1, N);
    // 5. aggregate 2: bufB
    k_selfinit<<<((size_t)N * 32 + B - 1) / B, B, 0, stream>>>(bufA, dinv, bufB, N);
    k_scatter<<<((size_t)E * 8 + B - 1) / B, B, 0, stream>>>(rows, cols, dinv, bufA, bufB, E);
    // 6. out = bufB @ W2 + b2
    k_out<<<((size_t)N * 64 + B - 1) / B, B, 0, stream>>>(bufB, W2, b2, out, N);
}

// Round 2
// 869.075 us; speedup vs baseline: 3.4487x; 3.4487x over previous
//
#include <hip/hip_runtime.h>
#include <math.h>

// GCN 2-layer on MI355X. N=100000, E=3200000, F_IN=256, HID=32, F_OUT=64.
// Strategy: CSR-by-destination counting sort (int atomics only), then
// gather-based aggregation (no float atomics). dinv folded into source:
//   agg(h)[i] = dinv[i] * ( sum_{j->i} g[j] + g[i] ),  g = dinv (.) h

__global__ void k_zero(int* p, int n) {
    int i = blockIdx.x * blockDim.x + threadIdx.x;
    if (i < n) p[i] = 0;
}

__global__ void k_count(const int* __restrict__ col, int* cnt, int e) {
    int i = blockIdx.x * blockDim.x + threadIdx.x;
    if (i < e) atomicAdd(&cnt[col[i]], 1);
}

__global__ void k_dinv(const int* __restrict__ cnt, float* __restrict__ dinv, int n) {
    int i = blockIdx.x * blockDim.x + threadIdx.x;
    if (i < n) dinv[i] = rsqrtf((float)(cnt[i] + 1));   // +1 self-loop
}

// exclusive scan, phase A: per-block (1024) Hillis-Steele
__global__ void k_scanA(const int* __restrict__ cnt, int* __restrict__ ptr,
                        int* __restrict__ bsum, int n) {
    __shared__ int sh[1024];
    int tid = threadIdx.x;
    int gid = blockIdx.x * 1024 + tid;
    int v = (gid < n) ? cnt[gid] : 0;
    sh[tid] = v;
    __syncthreads();
    for (int off = 1; off < 1024; off <<= 1) {
        int t = (tid >= off) ? sh[tid - off] : 0;
        __syncthreads();
        sh[tid] += t;
        __syncthreads();
    }
    if (gid < n) ptr[gid] = sh[tid] - v;            // exclusive
    if (tid == 1023) bsum[blockIdx.x] = sh[1023];   // block total
}

// phase B: serial exclusive scan of block sums (nb ~ 98)
__global__ void k_scanB(int* bsum, int nb) {
    if (blockIdx.x == 0 && threadIdx.x == 0) {
        int run = 0;
        for (int i = 0; i < nb; ++i) { int t = bsum[i]; bsum[i] = run; run += t; }
    }
}

// phase C: add block offsets; duplicate into fill[]; set ptr[n]=e
__global__ void k_scanC(int* __restrict__ ptr, int* __restrict__ fill,
                        const int* __restrict__ bsum, int n, int e) {
    int gid = blockIdx.x * blockDim.x + threadIdx.x;
    if (gid == 0) ptr[n] = e;
    if (gid < n) {
        int v = ptr[gid] + bsum[gid >> 10];
        ptr[gid] = v;
        fill[gid] = v;
    }
}

__global__ void k_scatter_ids(const int* __restrict__ rows, const int* __restrict__ cols,
                              int* fill, int* __restrict__ erow, int e) {
    int i = blockIdx.x * blockDim.x + threadIdx.x;
    if (i < e) {
        int pos = atomicAdd(&fill[cols[i]], 1);
        erow[pos] = rows[i];
    }
}

// g1 = dinv (.) (x @ W1): LDS-tiled, 32 nodes/block, 4 outputs/thread
__launch_bounds__(256)
__global__ void k_xw_g(const float4* __restrict__ x4, const float* __restrict__ W1,
                       const float* __restrict__ dinv, float* __restrict__ g1, int n) {
    __shared__ float xs[32 * 260];   // 32 rows, stride 260 (pad 4: bank-conflict-free, 16B aligned)
    int tid = threadIdx.x;
    int nb = blockIdx.x * 32;
#pragma unroll
    for (int t = 0; t < 8; ++t) {
        int idx = tid + t * 256;           // float4 idx in 32x64 tile
        int row = idx >> 6, c4 = idx & 63;
        float4 v = (nb + row < n) ? x4[(size_t)(nb + row) * 64 + c4]
                                  : make_float4(0.f, 0.f, 0.f, 0.f);
        *reinterpret_cast<float4*>(&xs[row * 260 + c4 * 4]) = v;
    }
    __syncthreads();
    int row = tid >> 3, k4 = tid & 7;
    int node = nb + row;
    if (node >= n) return;
    float s0 = 0.f, s1 = 0.f, s2 = 0.f, s3 = 0.f;
#pragma unroll 8
    for (int i = 0; i < 256; ++i) {
        float xv = xs[row * 260 + i];
        float4 w = *reinterpret_cast<const float4*>(&W1[i * 32 + k4 * 4]);
        s0 += xv * w.x; s1 += xv * w.y; s2 += xv * w.z; s3 += xv * w.w;
    }
    float d = dinv[node];
    *reinterpret_cast<float4*>(&g1[(size_t)node * 32 + k4 * 4]) =
        make_float4(d * s0, d * s1, d * s2, d * s3);
}

// layer-1 aggregate + bias + relu + pre-scale for layer 2:  g2 = dinv (.) relu(agg + b1)
__launch_bounds__(256)
__global__ void k_agg1(const float* __restrict__ g1, const int* __restrict__ erow,
                       const int* __restrict__ ptr, const float* __restrict__ dinv,
                       const float* __restrict__ b1, float* __restrict__ g2, int n) {
    int gid = blockIdx.x * blockDim.x + threadIdx.x;
    int node = gid >> 5, k = gid & 31;
    if (node >= n) return;
    float acc = g1[(size_t)node * 32 + k];           // self-loop term
    int s = ptr[node], e = ptr[node + 1];
    for (int t = s; t < e; ++t) {
        int r = erow[t];                              // broadcast within half-wave
        acc += g1[(size_t)r * 32 + k];                // coalesced 128B gather
    }
    float d = dinv[node];
    float h = fmaf(d, acc, b1[k]);
    h = h > 0.f ? h : 0.f;
    g2[gid] = d * h;
}

// layer-2 aggregate fused with W2 projection: out = (dinv.(sum g2)) @ W2 + b2
__launch_bounds__(256)
__global__ void k_agg2_out(const float* __restrict__ g2, const int* __restrict__ erow,
                           const int* __restrict__ ptr, const float* __restrict__ dinv,
                           const float* __restrict__ W2, const float* __restrict__ b2,
                           float* __restrict__ out, int n) {
    __shared__ float fr[8][33];
    __shared__ float w2s[32 * 64];
    int tid = threadIdx.x;
    for (int t = tid; t < 32 * 64; t += 256) w2s[t] = W2[t];
    int g = tid >> 5, k = tid & 31;
    int node = blockIdx.x * 8 + g;
    float v = 0.f;
    if (node < n) {
        float acc = g2[(size_t)node * 32 + k];
        int s = ptr[node], e = ptr[node + 1];
        for (int t = s; t < e; ++t) acc += g2[(size_t)erow[t] * 32 + k];
        v = dinv[node] * acc;
    }
    fr[g][k] = v;
    __syncthreads();
    if (node < n) {
        float s0 = b2[k], s1 = b2[k + 32];
#pragma unroll
        for (int i = 0; i < 32; ++i) {
            float f = fr[g][i];
            s0 = fmaf(f, w2s[i * 64 + k], s0);
            s1 = fmaf(f, w2s[i * 64 + k + 32], s1);
        }
        out[(size_t)node * 64 + k] = s0;
        out[(size_t)node * 64 + k + 32] = s1;
    }
}

extern "C" void kernel_launch(void* const* d_in, const int* in_sizes, int n_in,
                              void* d_out, int out_size, void* d_ws, size_t ws_size,
                              hipStream_t stream) {
    const float* x  = (const float*)d_in[0];
    const int*   ei = (const int*)d_in[1];
    const float* W1 = (const float*)d_in[2];
    const float* b1 = (const float*)d_in[3];
    const float* W2 = (const float*)d_in[4];
    const float* b2 = (const float*)d_in[5];
    float* out = (float*)d_out;

    const int N = in_sizes[0] / 256;
    const int E = in_sizes[1] / 2;
    const int* rows = ei;        // edge_index[0] (source)
    const int* cols = ei + E;    // edge_index[1] (dest)

    // workspace layout (4B units):
    // dinv[N] | ptr[N+1] | cnt/fill[N] | bsum[1024] | g1[N*32] | g2[N*32] | erow[E]
    float* dinv = (float*)d_ws;
    int*   ptr  = (int*)(dinv + N);
    int*   cnt  = ptr + (N + 1);          // reused as fill[] after scan
    int*   bsum = cnt + N;
    float* g1   = (float*)(bsum + 1024);
    float* g2   = g1 + (size_t)N * 32;
    int*   erow = (int*)(g2 + (size_t)N * 32);

    const int B = 256;
    const int nb1024 = (N + 1023) / 1024;

    k_zero<<<(N + B - 1) / B, B, 0, stream>>>(cnt, N);
    k_count<<<(E + B - 1) / B, B, 0, stream>>>(cols, cnt, E);
    k_dinv<<<(N + B - 1) / B, B, 0, stream>>>(cnt, dinv, N);
    k_scanA<<<nb1024, 1024, 0, stream>>>(cnt, ptr, bsum, N);
    k_scanB<<<1, 64, 0, stream>>>(bsum, nb1024);
    k_scanC<<<(N + B - 1) / B, B, 0, stream>>>(ptr, cnt, bsum, N, E);   // cnt -> fill
    k_scatter_ids<<<(E + B - 1) / B, B, 0, stream>>>(rows, cols, cnt, erow, E);
    k_xw_g<<<(N + 31) / 32, B, 0, stream>>>((const float4*)x, W1, dinv, g1, N);
    k_agg1<<<((size_t)N * 32 + B - 1) / B, B, 0, stream>>>(g1, erow, ptr, dinv, b1, g2, N);
    k_agg2_out<<<(N + 7) / 8, B, 0, stream>>>(g2, erow, ptr, dinv, W2, b2, out, N);
}